// Round 12
// baseline (114.032 us; speedup 1.0000x reference)
//
#include <hip/hip_runtime.h>

// CAttention on MI355X (gfx950). Inputs f32, output f32.
// Q = box3(x)*log2(e), K = V = normalize(x+EPS), softmax over keys, per batch.
// Round 27: occupancy attack via h=1. R11 flash (~41us) is latency-bound: MFMA floor
// 40k cyc/CU, LDS 17k, measured 98k at 2 waves/SIMD (h=2's ~150 regs pins occupancy).
// h=1 halves per-wave state (~90 regs < 128 cap) -> launch_bounds(512,4) -> 2x 8-wave
// blocks/CU = 4 waves/SIMD. LDS reads double (33k cyc/CU) but stay under the 40k MFMA
// floor -> rides the idle pipe. Structure = verified R24 dbuf (1 barrier/tile, prefetch
// after barrier), LDS 65536B, grid 512 @ S=4 = 2/CU, XCD grouping kept (bijective).
// prep/combine byte-identical to R11. Tripwire: FETCH>50MB = spill -> revert R11.
// ws: kmat bf16 @0 | kT bf16 @4M | xbT bf16 @8M | lsum f32 @12M | opart bf16 @13M (S*4M).

typedef short bf16x8 __attribute__((ext_vector_type(8)));
typedef float f32x4 __attribute__((ext_vector_type(4)));
typedef unsigned short u16x8 __attribute__((ext_vector_type(8)));
typedef unsigned int u32x4 __attribute__((ext_vector_type(4)));

#define L2E 1.4426950408889634f

__device__ __forceinline__ unsigned short f2bf(float f) {
    unsigned int u;
    __builtin_memcpy(&u, &f, 4);
    u = u + 0x7FFFu + ((u >> 16) & 1u);   // RNE
    return (unsigned short)(u >> 16);
}
__device__ __forceinline__ float bf2f(unsigned short h) {
    unsigned int u = ((unsigned int)h) << 16;
    float f;
    __builtin_memcpy(&f, &u, 4);
    return f;
}
__device__ __forceinline__ unsigned int pk_bf16(float a, float b) {
    unsigned int ua, ub;
    __builtin_memcpy(&ua, &a, 4);
    __builtin_memcpy(&ub, &b, 4);
    return ((ua + 0x8000u) >> 16) | ((ub + 0x8000u) & 0xFFFF0000u);
}
// async global->LDS, 16B/lane; lptr wave-uniform (HW dst = lptr + lane*16)
__device__ __forceinline__ void gl_lds16(const unsigned short* g, unsigned short* l) {
    __builtin_amdgcn_global_load_lds(
        (const __attribute__((address_space(1))) unsigned int*)g,
        (__attribute__((address_space(3))) unsigned int*)l, 16, 0, 0);
}
// async global->LDS, 4B/lane; g is per-lane, l wave-uniform (HW dst = l + lane*4)
__device__ __forceinline__ void gl_lds4(const float* g, float* l) {
    __builtin_amdgcn_global_load_lds(
        (const __attribute__((address_space(1))) unsigned int*)g,
        (__attribute__((address_space(3))) unsigned int*)l, 4, 0, 0);
}

// ---------------- K1: fused prep, async-DMA double-buffered chunks -----------------------
// grid (64 p, 4 b) x 512: block = one p-row (64 q), all 128 c in 8 chunks of 16.
__global__ void __launch_bounds__(512) prep(const float* __restrict__ x,
                     unsigned short* __restrict__ kmat,
                     unsigned short* __restrict__ kT,
                     unsigned short* __restrict__ xbT) {
    const int p = blockIdx.x, b = blockIdx.y;
    const int t = threadIdx.x, wave = t >> 6, lane = t & 63;

    __shared__ float sX[2][16][3][66];    // double-buffered chunk: 16 ch x 3 rows x 64+halo
    __shared__ float sMidT[64 * 132];     // [q][c], f32, stride 132
    __shared__ __align__(16) unsigned short sQ[64 * 136];
    __shared__ float sqp[512];
    __shared__ float sInv[64];

    // zero the q-halo columns once (DMA only ever writes elements [1..64])
    if (t < 192) {
        int bu = t / 96, u = t % 96, side = u & 1, v = u >> 1;   // v < 48
        int r = v % 3, cc = v / 3;
        sX[bu][cc][r][side * 65] = 0.f;
    }

    // issue chunk 0 DMA (wave-uniform (cc,r) per issue; 1 row = 64 lanes x 4B)
#pragma unroll
    for (int i = 0; i < 6; i++) {
        int pair = wave * 6 + i;
        int cc = pair / 3, r = pair - cc * 3, pp = p + r - 1;
        if ((unsigned)pp < 64u)
            gl_lds4(x + ((size_t)(b * 128 + cc) * 4096 + pp * 64) + lane,
                    &sX[0][cc][r][1]);
        else
            sX[0][cc][r][1 + lane] = 0.f;
    }

    float sqacc = 0.f;
    for (int k = 0; k < 8; k++) {
        __syncthreads();                              // chunk k DMA + writes drained
        if (k < 7) {                                  // issue chunk k+1 into other buffer
            int c0n = (k + 1) * 16, bn = (k + 1) & 1;
#pragma unroll
            for (int i = 0; i < 6; i++) {
                int pair = wave * 6 + i;
                int cc = pair / 3, r = pair - cc * 3, pp = p + r - 1;
                if ((unsigned)pp < 64u)
                    gl_lds4(x + ((size_t)(b * 128 + c0n + cc) * 4096 + pp * 64) + lane,
                            &sX[bn][cc][r][1]);
                else
                    sX[bn][cc][r][1 + lane] = 0.f;
            }
        }
        const int c0 = k * 16, kb = k & 1;
#pragma unroll
        for (int j = 0; j < 2; j++) {
            int cc = wave * 2 + j;
            float mid = sX[kb][cc][1][1 + lane] + 1e-7f;
            sMidT[lane * 132 + c0 + cc] = mid;
            sqacc += mid * mid;
            float sbox = 0.f;
#pragma unroll
            for (int r = 0; r < 3; r++)
                sbox += sX[kb][cc][r][lane] + sX[kb][cc][r][lane + 1] + sX[kb][cc][r][lane + 2];
            sQ[lane * 136 + c0 + cc] = f2bf(sbox * L2E);
        }
    }
    sqp[t] = sqacc;
    __syncthreads();
    if (t < 64) {
        float s = 0.f;
#pragma unroll
        for (int w = 0; w < 8; w++) s += sqp[w * 64 + t];
        sInv[t] = rsqrtf(s);
    }
    __syncthreads();

    // xbT in MFMA-fragment order: elem(b, qtile, cc, l16, quad, j) at
    // ((qtile*4+cc)*64 + l16*4 + quad)*8 + j  => Q[q=qtile*16+l16][c=cc*32+quad*8+j]
#pragma unroll
    for (int i = 0; i < 2; i++) {
        int u = i * 512 + t, row = u >> 4, g = u & 15;   // g = cc*4+quad
        int off = (((p * 4 + (row >> 4)) * 4 + (g >> 2)) * 64 + (row & 15) * 4 + (g & 3)) * 8;
        *(bf16x8*)(xbT + (size_t)b * 524288 + off) =
            *(const bf16x8*)(sQ + row * 136 + g * 8);
    }
    // kmat rows PERMUTED within the 64-key tile: position pos holds key perm(pos),
    // perm(pos) = (k4&1)*32 + quad*8 + (k4>>1)*4 + r  (k4=pos>>4, quad=(pos>>2)&3, r=pos&3)
    // 16B chunk G stored at G ^ (pos&15) (matches flash's ^l16 read swizzle).
#pragma unroll
    for (int i = 0; i < 2; i++) {
        int u = i * 512 + t, pos = u >> 4, G = u & 15;
        int k4 = pos >> 4, sub = pos & 15;
        int src = (k4 & 1) * 32 + (sub >> 2) * 8 + (k4 >> 1) * 4 + (sub & 3);
        float iv = sInv[src];
        f32x4 a = *(const f32x4*)(sMidT + src * 132 + G * 8);
        f32x4 c = *(const f32x4*)(sMidT + src * 132 + G * 8 + 4);
        unsigned int w[4];
        w[0] = pk_bf16(a[0] * iv, a[1] * iv);
        w[1] = pk_bf16(a[2] * iv, a[3] * iv);
        w[2] = pk_bf16(c[0] * iv, c[1] * iv);
        w[3] = pk_bf16(c[2] * iv, c[3] * iv);
        int Gs = G ^ (pos & 15);
        *(uint4*)(kmat + ((size_t)b * 4096 + p * 64 + pos) * 128 + Gs * 8) =
            make_uint4(w[0], w[1], w[2], w[3]);
    }
    // kT rows (V, natural key order): within each 64-key tile, 8-key chunk h at h ^ (c&7)
    {
        int cl = t >> 2, qg = t & 3;
        unsigned int w[8];
#pragma unroll
        for (int j = 0; j < 8; j++) {
            int ql = qg * 16 + j * 2;
            w[j] = pk_bf16(sMidT[ql * 132 + cl] * sInv[ql],
                           sMidT[(ql + 1) * 132 + cl] * sInv[ql + 1]);
        }
        unsigned short* dst = kT + ((size_t)b * 128 + cl) * 4096 + p * 64;
        int h0 = (qg * 2) ^ (cl & 7), h1 = (qg * 2 + 1) ^ (cl & 7);
        *(uint4*)(dst + h0 * 8) = make_uint4(w[0], w[1], w[2], w[3]);
        *(uint4*)(dst + h1 * 8) = make_uint4(w[4], w[5], w[6], w[7]);
    }
}

// ---------------- K2: split-K flash, h=1 (16 q/wave), dbuf, 2 blocks/CU ------------------
#define BUF_STRIDE 16384               // u16: one tile = sK 8192 + sV 8192
#define SMEM_ELEMS 32768               // u16 = 65536 B -> 2 blocks/CU (131072 <= 163840)

__global__ void __launch_bounds__(512, 4) flash_attn(
        const unsigned short* __restrict__ kmat,
        const unsigned short* __restrict__ kT,
        const unsigned short* __restrict__ xbT,
        unsigned short* __restrict__ opart,
        float* __restrict__ lsum,
        int nsplit, int qbshift) {
    // XCD-aware decode: idx%8 = XCD slot; all 32 qb-blocks of a (split,b) group share
    // one slot -> group's kmat/kT working set L2-resident. Bijective for S in {2,4}.
    const int idx = blockIdx.x;
    const int xs = idx & 7, j = idx >> 3;
    const int qb = j & 31;                          // 128-query tile, 0..31
    const int grp = xs * (nsplit >> 1) + (j >> 5);  // 0..4*nsplit-1
    const int split = grp >> 2, b = grp & 3;
    const int nk = 4096 / nsplit, NIT = nk >> 6, kt_base = split * nk;
    const int t = threadIdx.x;
    const int wave = t >> 6, lane = t & 63;         // wave 0..7
    const int l16 = lane & 15, quad = lane >> 4;

    __shared__ __align__(16) unsigned short smem[SMEM_ELEMS];

    // Q frags from fragment-ordered xbT: qtile = qb*8 + wave (16 q per wave)
    const unsigned short* xqb = xbT + (size_t)b * 524288 +
                                (size_t)(qb * 8 + wave) * 2048 + (l16 * 4 + quad) * 8;
    bf16x8 aq[4];
#pragma unroll
    for (int cc = 0; cc < 4; cc++)
        aq[cc] = *(const bf16x8*)(xqb + cc * 512);

    f32x4 o[8];
#pragma unroll
    for (int n = 0; n < 8; n++) o[n] = (f32x4){0.f, 0.f, 0.f, 0.f};
    float rs = 0.f;

    const unsigned short* kmb = kmat + (size_t)b * 4096 * 128;
    const unsigned short* ktb = kT + (size_t)b * 128 * 4096;

    // preload tile 0 into buffer 0 (8 waves cover K 16KB + V 16KB in 2 issues each)
    {
        const unsigned short* gK = kmb + (size_t)kt_base * 128;
#pragma unroll
        for (int i = 0; i < 2; i++) {
            int e = i * 4096 + t * 8;
            gl_lds16(gK + e, smem + i * 4096 + wave * 512);
            gl_lds16(ktb + (size_t)(e >> 6) * 4096 + kt_base + (e & 63),
                     smem + 8192 + i * 4096 + wave * 512);
        }
    }

    for (int it = 0; it < NIT; it++) {
        const int base = (it & 1) * BUF_STRIDE;
        unsigned short* sK = smem + base;                 // [64 key-pos][128], swizzled
        unsigned short* sV = smem + base + 8192;          // [128 c][64 key], swizzled

        // sole barrier: drains this tile's DMA; all waves past it -> other buffer reusable
        __syncthreads();

        // issue next tile's DMA immediately: latency window = QK + softmax + PV
        if (it + 1 < NIT) {
            const int kt0 = kt_base + (it + 1) * 64;
            unsigned short* nb = smem + ((it + 1) & 1) * BUF_STRIDE;
            const unsigned short* gK = kmb + (size_t)kt0 * 128;
#pragma unroll
            for (int i = 0; i < 2; i++) {
                int e = i * 4096 + t * 8;
                gl_lds16(gK + e, nb + i * 4096 + wave * 512);
                gl_lds16(ktb + (size_t)(e >> 6) * 4096 + kt0 + (e & 63),
                         nb + 8192 + i * 4096 + wave * 512);
            }
        }

        // S^T = K Q^T: lane holds S^T[pos = k4*16 + quad*4 + r][q = l16];
        // pos maps to key perm(pos) = (k4&1)*32 + quad*8 + (k4>>1)*4 + r.
        f32x4 s[4];
#pragma unroll
        for (int k4 = 0; k4 < 4; k4++) s[k4] = (f32x4){0.f, 0.f, 0.f, 0.f};
        __builtin_amdgcn_s_setprio(1);
#pragma unroll
        for (int cc = 0; cc < 4; cc++) {
#pragma unroll
            for (int k4 = 0; k4 < 4; k4++) {
                bf16x8 ak = *(const bf16x8*)(sK + (k4 * 16 + l16) * 128 +
                                             (((cc * 4 + quad) ^ l16) * 8));
                s[k4] = __builtin_amdgcn_mfma_f32_16x16x32_bf16(ak, aq[cc], s[k4], 0, 0, 0);
            }
        }
        __builtin_amdgcn_s_setprio(0);

        // p = 2^s; row-sum; pack straight into PV B-operand fragments (no LDS):
        // pa[kc][j] = P[key = kc*32 + quad*8 + j][q=l16]:
        //   j=0..3 from s[kc][r], j=4..7 from s[kc+2][r].
        float pv[4][4];
#pragma unroll
        for (int k4 = 0; k4 < 4; k4++) {
#pragma unroll
            for (int r = 0; r < 4; r++) {
                float p = __builtin_amdgcn_exp2f(s[k4][r]);
                pv[k4][r] = p;
                rs += p;
            }
        }
        bf16x8 pa[2];
#pragma unroll
        for (int kc = 0; kc < 2; kc++) {
            u32x4 w;
            w[0] = pk_bf16(pv[kc][0], pv[kc][1]);
            w[1] = pk_bf16(pv[kc][2], pv[kc][3]);
            w[2] = pk_bf16(pv[kc + 2][0], pv[kc + 2][1]);
            w[3] = pk_bf16(pv[kc + 2][2], pv[kc + 2][3]);
            pa[kc] = __builtin_bit_cast(bf16x8, w);
        }

        // O[c][q] += V^T P : A = V^T rows from sV (swizzled), B = pa (registers).
        __builtin_amdgcn_s_setprio(1);
#pragma unroll
        for (int kc = 0; kc < 2; kc++)
#pragma unroll
            for (int n = 0; n < 8; n++) {
                bf16x8 av = *(const bf16x8*)(sV + (n * 16 + l16) * 64 +
                                             (((kc * 4 + quad) ^ (l16 & 7)) * 8));
                o[n] = __builtin_amdgcn_mfma_f32_16x16x32_bf16(av, pa[kc], o[n], 0, 0, 0);
            }
        __builtin_amdgcn_s_setprio(0);
    }

    // row-sum reduce across quads; store lsum
    rs += __shfl_xor(rs, 16);
    rs += __shfl_xor(rs, 32);
    if (lane < 16)
        lsum[(size_t)(split * 4 + b) * 4096 + qb * 128 + wave * 16 + lane] = rs;

    // epilogue: o[n][r] = O[c = n*16+quad*4+r][q = wave*16+l16].
    // stage sO [128 q][136 c] u16 = 34816 B (aliases smem), then coalesced [q][c] store.
    __syncthreads();
    unsigned short* sO = smem;
    unsigned int* sO32 = (unsigned int*)smem;
    {
        int q = wave * 16 + l16;
#pragma unroll
        for (int n = 0; n < 8; n++) {
            int cb = n * 16 + quad * 4;
            sO32[(q * 136 + cb) >> 1] = pk_bf16(o[n][0], o[n][1]);
            sO32[(q * 136 + cb + 2) >> 1] = pk_bf16(o[n][2], o[n][3]);
        }
    }
    __syncthreads();
#pragma unroll
    for (int i = 0; i < 4; i++) {
        int u = i * 512 + t, q = u >> 4, ch = u & 15;
        *(uint4*)(opart + ((size_t)(split * 4 + b) * 4096 + qb * 128 + q) * 128 + ch * 8) =
            *(const uint4*)(sO + q * 136 + ch * 8);
    }
}

// ---------------- K3: combine splits + mask blend (opart [q][c]) -------------------------
// grid (64 qb64, 4 b, 2 cz) x 256: block = 64 q x 64 c. LDS transpose stage.
__global__ void combine(const unsigned short* __restrict__ opart,
                        const float* __restrict__ lsum,
                        const float* __restrict__ x,
                        const float* __restrict__ mask,
                        float* __restrict__ out, int S) {
    const int qb = blockIdx.x, b = blockIdx.y, cz = blockIdx.z, t = threadIdx.x;
    __shared__ float Linv[64];
    __shared__ float sAcc[64][73];       // [q local][c local], +pad for transpose reads
    if (t < 64) {
        float L = 0.f;
        for (int s2 = 0; s2 < S; s2++)
            L += lsum[(size_t)(s2 * 4 + b) * 4096 + qb * 64 + t];
        Linv[t] = 1.f / fmaxf(L, 1e-37f);
    }
    // phase 1: coalesced opart [q][c] reads, split-sum, stage to LDS
#pragma unroll
    for (int i = 0; i < 2; i++) {
        int u = i * 256 + t, qr = u >> 3, ch = u & 7;
        const unsigned short* ob = opart +
            ((size_t)b * 4096 + qb * 64 + qr) * 128 + cz * 64 + ch * 8;
        float acc[8] = {0.f, 0.f, 0.f, 0.f, 0.f, 0.f, 0.f, 0.f};
        if (S == 4) {
            u16x8 p0 = *(const u16x8*)(ob);
            u16x8 p1 = *(const u16x8*)(ob + (size_t)1 * 2097152);
            u16x8 p2 = *(const u16x8*)(ob + (size_t)2 * 2097152);
            u16x8 p3 = *(const u16x8*)(ob + (size_t)3 * 2097152);
#pragma unroll
            for (int j = 0; j < 8; j++)
                acc[j] = (bf2f(p0[j]) + bf2f(p1[j])) + (bf2f(p2[j]) + bf2f(p3[j]));
        } else {
            for (int s2 = 0; s2 < S; s2++) {
                u16x8 pv = *(const u16x8*)(ob + (size_t)s2 * 2097152);
#pragma unroll
                for (int j = 0; j < 8; j++) acc[j] += bf2f(pv[j]);
            }
        }
#pragma unroll
        for (int j = 0; j < 8; j++) sAcc[qr][ch * 8 + j] = acc[j];
    }
    __syncthreads();
    // phase 2: transposed LDS reads (padded stride), blend with x/mask (coalesced)
#pragma unroll
    for (int i = 0; i < 2; i++) {
        int u = i * 256 + t, cl = u >> 3, c = cz * 64 + cl, qc = u & 7;
        size_t qoff = (size_t)qb * 64 + qc * 8;
        const float* xr = x + ((size_t)b * 128 + c) * 4096 + qoff;
        const float* mr = mask + (size_t)b * 4096 + qoff;
        float* outr = out + ((size_t)b * 128 + c) * 4096 + qoff;
#pragma unroll
        for (int half = 0; half < 2; half++) {
            f32x4 xv = *(const f32x4*)(xr + half * 4);
            f32x4 mv = *(const f32x4*)(mr + half * 4);
            f32x4 res;
#pragma unroll
            for (int j = 0; j < 4; j++) {
                int ql = qc * 8 + half * 4 + j;
                res[j] = sAcc[ql][cl] * Linv[ql] *
                         (1.f - mv[j]) * (1.f / 9.f) + xv[j] * mv[j];
            }
            *(f32x4*)(outr + half * 4) = res;
        }
    }
}

extern "C" void kernel_launch(void* const* d_in, const int* in_sizes, int n_in,
                              void* d_out, int out_size, void* d_ws, size_t ws_size,
                              hipStream_t stream) {
    const float* x = (const float*)d_in[0];     // f32 (4,128,64,64)
    const float* mask = (const float*)d_in[1];  // f32 (4,1,64,64)
    float* out = (float*)d_out;                 // f32 (4,128,64,64)
    char* ws = (char*)d_ws;
    unsigned short* kmat = (unsigned short*)(ws);
    unsigned short* kT   = (unsigned short*)(ws + (size_t)4 * 1024 * 1024);
    unsigned short* xbT  = (unsigned short*)(ws + (size_t)8 * 1024 * 1024);
    float* lsum          = (float*)(ws + (size_t)12 * 1024 * 1024);
    unsigned short* opart = (unsigned short*)(ws + (size_t)13 * 1024 * 1024);

    // ws need: 13 MiB + S*4 MiB; S=4 -> flash grid 32*4*4 = 512 blocks = 2/CU
    int S, qbshift;
    if (ws_size >= (size_t)29 * 1024 * 1024)      { S = 4; qbshift = 4; }
    else if (ws_size >= (size_t)21 * 1024 * 1024) { S = 2; qbshift = 3; }
    else return;

    prep<<<dim3(64, 4), 512, 0, stream>>>(x, kmat, kT, xbT);
    flash_attn<<<dim3(32 * 4 * S), 512, 0, stream>>>(kmat, kT, xbT, opart, lsum, S, qbshift);
    combine<<<dim3(64, 4, 2), 256, 0, stream>>>(opart, lsum, x, mask, out, S);
}

// Round 13
// 111.095 us; speedup vs baseline: 1.0264x; 1.0264x over previous
//
#include <hip/hip_runtime.h>

// CAttention on MI355X (gfx950). Inputs f32, output f32.
// Q = box3(x)*log2(e), K = V = normalize(x+EPS), softmax over keys, per batch.
// Round 28: exact revert to R26/R11 (verified best, 111.4us total). R27's h=1
// falsified the occupancy lever: LDS-read doubling (reuse 2->1) cost more than
// 2x TLP gained (+2.6us). Design space now mapped: h=2 @ 8 waves/CU is the
// register-constrained optimum (regs/wave x waves <= 2048; o-accumulator scales
// with q/wave exactly as LDS reuse does). Flash ~41us = latency plateau, all
// pipes <35%; occupancy/reuse blocked both directions by the register file.
// Structure: pair-barriers (1 barrier / 2 tiles, 128KiB LDS), XCD-grouped decode,
// P-in-registers via key permutation (no sP roundtrip), async-DMA prep,
// transpose-staged combine.
// ws: kmat bf16 @0 | kT bf16 @4M | xbT bf16 @8M | lsum f32 @12M | opart bf16 @13M (S*4M).

typedef short bf16x8 __attribute__((ext_vector_type(8)));
typedef float f32x4 __attribute__((ext_vector_type(4)));
typedef unsigned short u16x8 __attribute__((ext_vector_type(8)));
typedef unsigned int u32x4 __attribute__((ext_vector_type(4)));

#define L2E 1.4426950408889634f

__device__ __forceinline__ unsigned short f2bf(float f) {
    unsigned int u;
    __builtin_memcpy(&u, &f, 4);
    u = u + 0x7FFFu + ((u >> 16) & 1u);   // RNE
    return (unsigned short)(u >> 16);
}
__device__ __forceinline__ float bf2f(unsigned short h) {
    unsigned int u = ((unsigned int)h) << 16;
    float f;
    __builtin_memcpy(&f, &u, 4);
    return f;
}
__device__ __forceinline__ unsigned int pk_bf16(float a, float b) {
    unsigned int ua, ub;
    __builtin_memcpy(&ua, &a, 4);
    __builtin_memcpy(&ub, &b, 4);
    return ((ua + 0x8000u) >> 16) | ((ub + 0x8000u) & 0xFFFF0000u);
}
// async global->LDS, 16B/lane; lptr wave-uniform (HW dst = lptr + lane*16)
__device__ __forceinline__ void gl_lds16(const unsigned short* g, unsigned short* l) {
    __builtin_amdgcn_global_load_lds(
        (const __attribute__((address_space(1))) unsigned int*)g,
        (__attribute__((address_space(3))) unsigned int*)l, 16, 0, 0);
}
// async global->LDS, 4B/lane; g is per-lane, l wave-uniform (HW dst = l + lane*4)
__device__ __forceinline__ void gl_lds4(const float* g, float* l) {
    __builtin_amdgcn_global_load_lds(
        (const __attribute__((address_space(1))) unsigned int*)g,
        (__attribute__((address_space(3))) unsigned int*)l, 4, 0, 0);
}

// ---------------- K1: fused prep, async-DMA double-buffered chunks -----------------------
// grid (64 p, 4 b) x 512: block = one p-row (64 q), all 128 c in 8 chunks of 16.
__global__ void __launch_bounds__(512) prep(const float* __restrict__ x,
                     unsigned short* __restrict__ kmat,
                     unsigned short* __restrict__ kT,
                     unsigned short* __restrict__ xbT) {
    const int p = blockIdx.x, b = blockIdx.y;
    const int t = threadIdx.x, wave = t >> 6, lane = t & 63;

    __shared__ float sX[2][16][3][66];    // double-buffered chunk: 16 ch x 3 rows x 64+halo
    __shared__ float sMidT[64 * 132];     // [q][c], f32, stride 132
    __shared__ __align__(16) unsigned short sQ[64 * 136];
    __shared__ float sqp[512];
    __shared__ float sInv[64];

    // zero the q-halo columns once (DMA only ever writes elements [1..64])
    if (t < 192) {
        int bu = t / 96, u = t % 96, side = u & 1, v = u >> 1;   // v < 48
        int r = v % 3, cc = v / 3;
        sX[bu][cc][r][side * 65] = 0.f;
    }

    // issue chunk 0 DMA (wave-uniform (cc,r) per issue; 1 row = 64 lanes x 4B)
#pragma unroll
    for (int i = 0; i < 6; i++) {
        int pair = wave * 6 + i;
        int cc = pair / 3, r = pair - cc * 3, pp = p + r - 1;
        if ((unsigned)pp < 64u)
            gl_lds4(x + ((size_t)(b * 128 + cc) * 4096 + pp * 64) + lane,
                    &sX[0][cc][r][1]);
        else
            sX[0][cc][r][1 + lane] = 0.f;
    }

    float sqacc = 0.f;
    for (int k = 0; k < 8; k++) {
        __syncthreads();                              // chunk k DMA + writes drained
        if (k < 7) {                                  // issue chunk k+1 into other buffer
            int c0n = (k + 1) * 16, bn = (k + 1) & 1;
#pragma unroll
            for (int i = 0; i < 6; i++) {
                int pair = wave * 6 + i;
                int cc = pair / 3, r = pair - cc * 3, pp = p + r - 1;
                if ((unsigned)pp < 64u)
                    gl_lds4(x + ((size_t)(b * 128 + c0n + cc) * 4096 + pp * 64) + lane,
                            &sX[bn][cc][r][1]);
                else
                    sX[bn][cc][r][1 + lane] = 0.f;
            }
        }
        const int c0 = k * 16, kb = k & 1;
#pragma unroll
        for (int j = 0; j < 2; j++) {
            int cc = wave * 2 + j;
            float mid = sX[kb][cc][1][1 + lane] + 1e-7f;
            sMidT[lane * 132 + c0 + cc] = mid;
            sqacc += mid * mid;
            float sbox = 0.f;
#pragma unroll
            for (int r = 0; r < 3; r++)
                sbox += sX[kb][cc][r][lane] + sX[kb][cc][r][lane + 1] + sX[kb][cc][r][lane + 2];
            sQ[lane * 136 + c0 + cc] = f2bf(sbox * L2E);
        }
    }
    sqp[t] = sqacc;
    __syncthreads();
    if (t < 64) {
        float s = 0.f;
#pragma unroll
        for (int w = 0; w < 8; w++) s += sqp[w * 64 + t];
        sInv[t] = rsqrtf(s);
    }
    __syncthreads();

    // xbT in MFMA-fragment order: elem(b, qtile, cc, l16, quad, j) at
    // ((qtile*4+cc)*64 + l16*4 + quad)*8 + j  => Q[q=qtile*16+l16][c=cc*32+quad*8+j]
#pragma unroll
    for (int i = 0; i < 2; i++) {
        int u = i * 512 + t, row = u >> 4, g = u & 15;   // g = cc*4+quad
        int off = (((p * 4 + (row >> 4)) * 4 + (g >> 2)) * 64 + (row & 15) * 4 + (g & 3)) * 8;
        *(bf16x8*)(xbT + (size_t)b * 524288 + off) =
            *(const bf16x8*)(sQ + row * 136 + g * 8);
    }
    // kmat rows PERMUTED within the 64-key tile: position pos holds key perm(pos),
    // perm(pos) = (k4&1)*32 + quad*8 + (k4>>1)*4 + r  (k4=pos>>4, quad=(pos>>2)&3, r=pos&3)
    // 16B chunk G stored at G ^ (pos&15) (matches flash's ^l16 read swizzle).
#pragma unroll
    for (int i = 0; i < 2; i++) {
        int u = i * 512 + t, pos = u >> 4, G = u & 15;
        int k4 = pos >> 4, sub = pos & 15;
        int src = (k4 & 1) * 32 + (sub >> 2) * 8 + (k4 >> 1) * 4 + (sub & 3);
        float iv = sInv[src];
        f32x4 a = *(const f32x4*)(sMidT + src * 132 + G * 8);
        f32x4 c = *(const f32x4*)(sMidT + src * 132 + G * 8 + 4);
        unsigned int w[4];
        w[0] = pk_bf16(a[0] * iv, a[1] * iv);
        w[1] = pk_bf16(a[2] * iv, a[3] * iv);
        w[2] = pk_bf16(c[0] * iv, c[1] * iv);
        w[3] = pk_bf16(c[2] * iv, c[3] * iv);
        int Gs = G ^ (pos & 15);
        *(uint4*)(kmat + ((size_t)b * 4096 + p * 64 + pos) * 128 + Gs * 8) =
            make_uint4(w[0], w[1], w[2], w[3]);
    }
    // kT rows (V, natural key order): within each 64-key tile, 8-key chunk h at h ^ (c&7)
    {
        int cl = t >> 2, qg = t & 3;
        unsigned int w[8];
#pragma unroll
        for (int j = 0; j < 8; j++) {
            int ql = qg * 16 + j * 2;
            w[j] = pk_bf16(sMidT[ql * 132 + cl] * sInv[ql],
                           sMidT[(ql + 1) * 132 + cl] * sInv[ql + 1]);
        }
        unsigned short* dst = kT + ((size_t)b * 128 + cl) * 4096 + p * 64;
        int h0 = (qg * 2) ^ (cl & 7), h1 = (qg * 2 + 1) ^ (cl & 7);
        *(uint4*)(dst + h0 * 8) = make_uint4(w[0], w[1], w[2], w[3]);
        *(uint4*)(dst + h1 * 8) = make_uint4(w[4], w[5], w[6], w[7]);
    }
}

// ---------------- K2: split-K flash, 512 thr, 2-tile barrier pairs, XCD-grouped ----------
#define TILE_STRIDE 16384              // u16: one tile = sK 8192 + sV 8192
#define PAIR_STRIDE 32768              // u16: two tiles
#define SMEM_ELEMS  65536              // u16 = 131072 B -> 1 block/CU (fits 160K pool)

__global__ void __launch_bounds__(512, 2) flash_attn(
        const unsigned short* __restrict__ kmat,
        const unsigned short* __restrict__ kT,
        const unsigned short* __restrict__ xbT,
        unsigned short* __restrict__ opart,
        float* __restrict__ lsum,
        int nsplit, int qbshift) {
    // XCD-aware decode: idx%8 = XCD slot; the 16 qb-blocks of each (split,b) group share
    // one slot -> group's kmat/kT working set stays in that XCD's L2. Bijective for S>=2.
    const int idx = blockIdx.x;
    const int xs = idx & 7, j = idx >> 3;
    const int qb = j & 15;                         // 256-query tile, 0..15
    const int grp = xs * (nsplit >> 1) + (j >> 4); // 0..4*nsplit-1
    const int split = grp >> 2, b = grp & 3;
    const int nk = 4096 / nsplit, NIT = nk >> 6, kt_base = split * nk;
    const int NPAIR = NIT >> 1;
    const int t = threadIdx.x;
    const int wave = t >> 6, lane = t & 63;        // wave 0..7
    const int l16 = lane & 15, quad = lane >> 4;

    __shared__ __align__(16) unsigned short smem[SMEM_ELEMS];

    // Q frags from fragment-ordered xbT: qtile = qb*16 + wave*2 + h (32 q per wave)
    const unsigned short* xqb = xbT + (size_t)b * 524288 +
                                (size_t)(qb * 16 + wave * 2) * 2048 + (l16 * 4 + quad) * 8;
    bf16x8 aq[2][4];
#pragma unroll
    for (int h = 0; h < 2; h++)
#pragma unroll
        for (int cc = 0; cc < 4; cc++)
            aq[h][cc] = *(const bf16x8*)(xqb + h * 2048 + cc * 512);

    f32x4 o[2][8];
#pragma unroll
    for (int h = 0; h < 2; h++)
#pragma unroll
        for (int n = 0; n < 8; n++) o[h][n] = (f32x4){0.f, 0.f, 0.f, 0.f};
    float rs[2] = {0.f, 0.f};

    const unsigned short* kmb = kmat + (size_t)b * 4096 * 128;
    const unsigned short* ktb = kT + (size_t)b * 128 * 4096;

    // preload pair 0 into pair-buffer 0 (per tile: 8 waves x 2 issues K + 2 issues V)
#pragma unroll
    for (int half = 0; half < 2; half++) {
        const int kt0 = kt_base + half * 64;
        unsigned short* nb = smem + half * TILE_STRIDE;
        const unsigned short* gK = kmb + (size_t)kt0 * 128;
#pragma unroll
        for (int i = 0; i < 2; i++) {
            int e = i * 4096 + t * 8;
            gl_lds16(gK + e, nb + i * 4096 + wave * 512);
            gl_lds16(ktb + (size_t)(e >> 6) * 4096 + kt0 + (e & 63),
                     nb + 8192 + i * 4096 + wave * 512);
        }
    }

    for (int ip = 0; ip < NPAIR; ip++) {
        const int base = (ip & 1) * PAIR_STRIDE;

        // sole barrier per PAIR: drains this pair's DMA; all waves past it -> other
        // pair-buffer fully read (pair ip-1 compute preceded this barrier) -> reusable.
        __syncthreads();

        // issue next pair's DMA immediately: latency window = two tiles of compute
        if (ip + 1 < NPAIR) {
            unsigned short* pb = smem + ((ip + 1) & 1) * PAIR_STRIDE;
#pragma unroll
            for (int half = 0; half < 2; half++) {
                const int kt0 = kt_base + (2 * (ip + 1) + half) * 64;
                unsigned short* nb = pb + half * TILE_STRIDE;
                const unsigned short* gK = kmb + (size_t)kt0 * 128;
#pragma unroll
                for (int i = 0; i < 2; i++) {
                    int e = i * 4096 + t * 8;
                    gl_lds16(gK + e, nb + i * 4096 + wave * 512);
                    gl_lds16(ktb + (size_t)(e >> 6) * 4096 + kt0 + (e & 63),
                             nb + 8192 + i * 4096 + wave * 512);
                }
            }
        }

#pragma unroll
        for (int sub = 0; sub < 2; sub++) {
            unsigned short* sK = smem + base + sub * TILE_STRIDE;   // [64 pos][128], swz
            unsigned short* sV = sK + 8192;                         // [128 c][64 key], swz

            // S^T = K Q^T: lane holds S^T[pos = k4*16 + quad*4 + r][q = l16];
            // pos maps to key perm(pos) = (k4&1)*32 + quad*8 + (k4>>1)*4 + r.
            f32x4 s[2][4];
#pragma unroll
            for (int h = 0; h < 2; h++)
#pragma unroll
                for (int k4 = 0; k4 < 4; k4++) s[h][k4] = (f32x4){0.f, 0.f, 0.f, 0.f};
            __builtin_amdgcn_s_setprio(1);
#pragma unroll
            for (int cc = 0; cc < 4; cc++) {
#pragma unroll
                for (int k4 = 0; k4 < 4; k4++) {
                    bf16x8 ak = *(const bf16x8*)(sK + (k4 * 16 + l16) * 128 +
                                                 (((cc * 4 + quad) ^ l16) * 8));
                    s[0][k4] = __builtin_amdgcn_mfma_f32_16x16x32_bf16(ak, aq[0][cc], s[0][k4], 0, 0, 0);
                    s[1][k4] = __builtin_amdgcn_mfma_f32_16x16x32_bf16(ak, aq[1][cc], s[1][k4], 0, 0, 0);
                }
            }
            __builtin_amdgcn_s_setprio(0);

            // p = 2^s; row-sum; pack straight into PV B-operand fragments (no LDS):
            // pa[h][kc][j] = P[key = kc*32 + quad*8 + j][q=l16]:
            //   j=0..3 from s[h][kc][r], j=4..7 from s[h][kc+2][r].
            bf16x8 pa[2][2];
#pragma unroll
            for (int h = 0; h < 2; h++) {
                float pv[4][4];
#pragma unroll
                for (int k4 = 0; k4 < 4; k4++) {
#pragma unroll
                    for (int r = 0; r < 4; r++) {
                        float p = __builtin_amdgcn_exp2f(s[h][k4][r]);
                        pv[k4][r] = p;
                        rs[h] += p;
                    }
                }
#pragma unroll
                for (int kc = 0; kc < 2; kc++) {
                    u32x4 w;
                    w[0] = pk_bf16(pv[kc][0], pv[kc][1]);
                    w[1] = pk_bf16(pv[kc][2], pv[kc][3]);
                    w[2] = pk_bf16(pv[kc + 2][0], pv[kc + 2][1]);
                    w[3] = pk_bf16(pv[kc + 2][2], pv[kc + 2][3]);
                    pa[h][kc] = __builtin_bit_cast(bf16x8, w);
                }
            }

            // O[c][q] += V^T P : A = V^T rows from sV (swizzled), B = pa (registers).
            __builtin_amdgcn_s_setprio(1);
#pragma unroll
            for (int kc = 0; kc < 2; kc++)
#pragma unroll
                for (int n = 0; n < 8; n++) {
                    bf16x8 av = *(const bf16x8*)(sV + (n * 16 + l16) * 64 +
                                                 (((kc * 4 + quad) ^ (l16 & 7)) * 8));
                    o[0][n] = __builtin_amdgcn_mfma_f32_16x16x32_bf16(av, pa[0][kc], o[0][n], 0, 0, 0);
                    o[1][n] = __builtin_amdgcn_mfma_f32_16x16x32_bf16(av, pa[1][kc], o[1][n], 0, 0, 0);
                }
            __builtin_amdgcn_s_setprio(0);
        }
    }

    // row-sums reduce across quads; store lsum
#pragma unroll
    for (int h = 0; h < 2; h++) {
        rs[h] += __shfl_xor(rs[h], 16);
        rs[h] += __shfl_xor(rs[h], 32);
    }
    if (lane < 16) {
#pragma unroll
        for (int h = 0; h < 2; h++)
            lsum[(size_t)(split * 4 + b) * 4096 + qb * 256 + wave * 32 + h * 16 + lane] = rs[h];
    }

    // epilogue: o[h][n][r] = O[c = n*16+quad*4+r][q = wave*32+h*16+l16].
    // stage sO [256 q][136 c] u16 = 69632 B (aliases smem), then coalesced [q][c] store.
    __syncthreads();
    unsigned short* sO = smem;
    unsigned int* sO32 = (unsigned int*)smem;
#pragma unroll
    for (int h = 0; h < 2; h++) {
        int q = wave * 32 + h * 16 + l16;
#pragma unroll
        for (int n = 0; n < 8; n++) {
            int cb = n * 16 + quad * 4;
            sO32[(q * 136 + cb) >> 1] = pk_bf16(o[h][n][0], o[h][n][1]);
            sO32[(q * 136 + cb + 2) >> 1] = pk_bf16(o[h][n][2], o[h][n][3]);
        }
    }
    __syncthreads();
#pragma unroll
    for (int i = 0; i < 8; i++) {
        int u = i * 512 + t, q = u >> 4, ch = u & 15;
        *(uint4*)(opart + ((size_t)(split * 4 + b) * 4096 + qb * 256 + q) * 128 + ch * 8) =
            *(const uint4*)(sO + q * 136 + ch * 8);
    }
}

// ---------------- K3: combine splits + mask blend (opart [q][c]) -------------------------
// grid (64 qb64, 4 b, 2 cz) x 256: block = 64 q x 64 c. LDS transpose stage.
__global__ void combine(const unsigned short* __restrict__ opart,
                        const float* __restrict__ lsum,
                        const float* __restrict__ x,
                        const float* __restrict__ mask,
                        float* __restrict__ out, int S) {
    const int qb = blockIdx.x, b = blockIdx.y, cz = blockIdx.z, t = threadIdx.x;
    __shared__ float Linv[64];
    __shared__ float sAcc[64][73];       // [q local][c local], +pad for transpose reads
    if (t < 64) {
        float L = 0.f;
        for (int s2 = 0; s2 < S; s2++)
            L += lsum[(size_t)(s2 * 4 + b) * 4096 + qb * 64 + t];
        Linv[t] = 1.f / fmaxf(L, 1e-37f);
    }
    // phase 1: coalesced opart [q][c] reads, split-sum, stage to LDS
#pragma unroll
    for (int i = 0; i < 2; i++) {
        int u = i * 256 + t, qr = u >> 3, ch = u & 7;
        const unsigned short* ob = opart +
            ((size_t)b * 4096 + qb * 64 + qr) * 128 + cz * 64 + ch * 8;
        float acc[8] = {0.f, 0.f, 0.f, 0.f, 0.f, 0.f, 0.f, 0.f};
        if (S == 4) {
            u16x8 p0 = *(const u16x8*)(ob);
            u16x8 p1 = *(const u16x8*)(ob + (size_t)1 * 2097152);
            u16x8 p2 = *(const u16x8*)(ob + (size_t)2 * 2097152);
            u16x8 p3 = *(const u16x8*)(ob + (size_t)3 * 2097152);
#pragma unroll
            for (int j = 0; j < 8; j++)
                acc[j] = (bf2f(p0[j]) + bf2f(p1[j])) + (bf2f(p2[j]) + bf2f(p3[j]));
        } else {
            for (int s2 = 0; s2 < S; s2++) {
                u16x8 pv = *(const u16x8*)(ob + (size_t)s2 * 2097152);
#pragma unroll
                for (int j = 0; j < 8; j++) acc[j] += bf2f(pv[j]);
            }
        }
#pragma unroll
        for (int j = 0; j < 8; j++) sAcc[qr][ch * 8 + j] = acc[j];
    }
    __syncthreads();
    // phase 2: transposed LDS reads (padded stride), blend with x/mask (coalesced)
#pragma unroll
    for (int i = 0; i < 2; i++) {
        int u = i * 256 + t, cl = u >> 3, c = cz * 64 + cl, qc = u & 7;
        size_t qoff = (size_t)qb * 64 + qc * 8;
        const float* xr = x + ((size_t)b * 128 + c) * 4096 + qoff;
        const float* mr = mask + (size_t)b * 4096 + qoff;
        float* outr = out + ((size_t)b * 128 + c) * 4096 + qoff;
#pragma unroll
        for (int half = 0; half < 2; half++) {
            f32x4 xv = *(const f32x4*)(xr + half * 4);
            f32x4 mv = *(const f32x4*)(mr + half * 4);
            f32x4 res;
#pragma unroll
            for (int j = 0; j < 4; j++) {
                int ql = qc * 8 + half * 4 + j;
                res[j] = sAcc[ql][cl] * Linv[ql] *
                         (1.f - mv[j]) * (1.f / 9.f) + xv[j] * mv[j];
            }
            *(f32x4*)(outr + half * 4) = res;
        }
    }
}

extern "C" void kernel_launch(void* const* d_in, const int* in_sizes, int n_in,
                              void* d_out, int out_size, void* d_ws, size_t ws_size,
                              hipStream_t stream) {
    const float* x = (const float*)d_in[0];     // f32 (4,128,64,64)
    const float* mask = (const float*)d_in[1];  // f32 (4,1,64,64)
    float* out = (float*)d_out;                 // f32 (4,128,64,64)
    char* ws = (char*)d_ws;
    unsigned short* kmat = (unsigned short*)(ws);
    unsigned short* kT   = (unsigned short*)(ws + (size_t)4 * 1024 * 1024);
    unsigned short* xbT  = (unsigned short*)(ws + (size_t)8 * 1024 * 1024);
    float* lsum          = (float*)(ws + (size_t)12 * 1024 * 1024);
    unsigned short* opart = (unsigned short*)(ws + (size_t)13 * 1024 * 1024);

    // ws need: 13 MiB + S*4 MiB; S=4 -> flash grid 16*4*4 = 256 blocks = 1/CU
    int S, qbshift;
    if (ws_size >= (size_t)29 * 1024 * 1024)      { S = 4; qbshift = 4; }
    else if (ws_size >= (size_t)21 * 1024 * 1024) { S = 2; qbshift = 3; }
    else return;

    prep<<<dim3(64, 4), 512, 0, stream>>>(x, kmat, kT, xbT);
    flash_attn<<<dim3(16 * 4 * S), 512, 0, stream>>>(kmat, kT, xbT, opart, lsum, S, qbshift);
    combine<<<dim3(64, 4, 2), 256, 0, stream>>>(opart, lsum, x, mask, out, S);
}

// Round 14
// 110.701 us; speedup vs baseline: 1.0301x; 1.0036x over previous
//
#include <hip/hip_runtime.h>

// CAttention on MI355X (gfx950). Inputs f32, output f32.
// Q = box3(x)*log2(e), K = V = normalize(x+EPS), softmax over keys, per batch.
// Round 29: R13 (verified best, 111.1us) + v_cvt_pk_bf16_f32 packing. pk_bf16 was
// ~5 VALU ops/pair; the HW packed convert is 1 (inline asm — no builtin on gfx950).
// Applied at flash softmax pack (16 pairs/tile/wave), flash epilogue (16 pairs), and
// prep kmat/kT stores (12 pairs/thread). Rounding half-up -> RNE (±1 bf16 ulp, benign).
// Everything else byte-identical to R13: pair-barriers (1 barrier / 2 tiles, 128KiB),
// XCD-grouped decode, P-in-registers key permutation, async-DMA prep, staged combine.
// ws: kmat bf16 @0 | kT bf16 @4M | xbT bf16 @8M | lsum f32 @12M | opart bf16 @13M (S*4M).

typedef short bf16x8 __attribute__((ext_vector_type(8)));
typedef float f32x4 __attribute__((ext_vector_type(4)));
typedef unsigned short u16x8 __attribute__((ext_vector_type(8)));
typedef unsigned int u32x4 __attribute__((ext_vector_type(4)));

#define L2E 1.4426950408889634f

__device__ __forceinline__ unsigned short f2bf(float f) {
    unsigned int u;
    __builtin_memcpy(&u, &f, 4);
    u = u + 0x7FFFu + ((u >> 16) & 1u);   // RNE
    return (unsigned short)(u >> 16);
}
__device__ __forceinline__ float bf2f(unsigned short h) {
    unsigned int u = ((unsigned int)h) << 16;
    float f;
    __builtin_memcpy(&f, &u, 4);
    return f;
}
// packed f32x2 -> bf16x2 (low16 from a, high16 from b), single HW instruction (RNE)
__device__ __forceinline__ unsigned int cvtpk(float a, float b) {
    unsigned int r;
    asm("v_cvt_pk_bf16_f32 %0, %1, %2" : "=v"(r) : "v"(a), "v"(b));
    return r;
}
// async global->LDS, 16B/lane; lptr wave-uniform (HW dst = lptr + lane*16)
__device__ __forceinline__ void gl_lds16(const unsigned short* g, unsigned short* l) {
    __builtin_amdgcn_global_load_lds(
        (const __attribute__((address_space(1))) unsigned int*)g,
        (__attribute__((address_space(3))) unsigned int*)l, 16, 0, 0);
}
// async global->LDS, 4B/lane; g is per-lane, l wave-uniform (HW dst = l + lane*4)
__device__ __forceinline__ void gl_lds4(const float* g, float* l) {
    __builtin_amdgcn_global_load_lds(
        (const __attribute__((address_space(1))) unsigned int*)g,
        (__attribute__((address_space(3))) unsigned int*)l, 4, 0, 0);
}

// ---------------- K1: fused prep, async-DMA double-buffered chunks -----------------------
// grid (64 p, 4 b) x 512: block = one p-row (64 q), all 128 c in 8 chunks of 16.
__global__ void __launch_bounds__(512) prep(const float* __restrict__ x,
                     unsigned short* __restrict__ kmat,
                     unsigned short* __restrict__ kT,
                     unsigned short* __restrict__ xbT) {
    const int p = blockIdx.x, b = blockIdx.y;
    const int t = threadIdx.x, wave = t >> 6, lane = t & 63;

    __shared__ float sX[2][16][3][66];    // double-buffered chunk: 16 ch x 3 rows x 64+halo
    __shared__ float sMidT[64 * 132];     // [q][c], f32, stride 132
    __shared__ __align__(16) unsigned short sQ[64 * 136];
    __shared__ float sqp[512];
    __shared__ float sInv[64];

    // zero the q-halo columns once (DMA only ever writes elements [1..64])
    if (t < 192) {
        int bu = t / 96, u = t % 96, side = u & 1, v = u >> 1;   // v < 48
        int r = v % 3, cc = v / 3;
        sX[bu][cc][r][side * 65] = 0.f;
    }

    // issue chunk 0 DMA (wave-uniform (cc,r) per issue; 1 row = 64 lanes x 4B)
#pragma unroll
    for (int i = 0; i < 6; i++) {
        int pair = wave * 6 + i;
        int cc = pair / 3, r = pair - cc * 3, pp = p + r - 1;
        if ((unsigned)pp < 64u)
            gl_lds4(x + ((size_t)(b * 128 + cc) * 4096 + pp * 64) + lane,
                    &sX[0][cc][r][1]);
        else
            sX[0][cc][r][1 + lane] = 0.f;
    }

    float sqacc = 0.f;
    for (int k = 0; k < 8; k++) {
        __syncthreads();                              // chunk k DMA + writes drained
        if (k < 7) {                                  // issue chunk k+1 into other buffer
            int c0n = (k + 1) * 16, bn = (k + 1) & 1;
#pragma unroll
            for (int i = 0; i < 6; i++) {
                int pair = wave * 6 + i;
                int cc = pair / 3, r = pair - cc * 3, pp = p + r - 1;
                if ((unsigned)pp < 64u)
                    gl_lds4(x + ((size_t)(b * 128 + c0n + cc) * 4096 + pp * 64) + lane,
                            &sX[bn][cc][r][1]);
                else
                    sX[bn][cc][r][1 + lane] = 0.f;
            }
        }
        const int c0 = k * 16, kb = k & 1;
#pragma unroll
        for (int j = 0; j < 2; j++) {
            int cc = wave * 2 + j;
            float mid = sX[kb][cc][1][1 + lane] + 1e-7f;
            sMidT[lane * 132 + c0 + cc] = mid;
            sqacc += mid * mid;
            float sbox = 0.f;
#pragma unroll
            for (int r = 0; r < 3; r++)
                sbox += sX[kb][cc][r][lane] + sX[kb][cc][r][lane + 1] + sX[kb][cc][r][lane + 2];
            sQ[lane * 136 + c0 + cc] = f2bf(sbox * L2E);
        }
    }
    sqp[t] = sqacc;
    __syncthreads();
    if (t < 64) {
        float s = 0.f;
#pragma unroll
        for (int w = 0; w < 8; w++) s += sqp[w * 64 + t];
        sInv[t] = rsqrtf(s);
    }
    __syncthreads();

    // xbT in MFMA-fragment order: elem(b, qtile, cc, l16, quad, j) at
    // ((qtile*4+cc)*64 + l16*4 + quad)*8 + j  => Q[q=qtile*16+l16][c=cc*32+quad*8+j]
#pragma unroll
    for (int i = 0; i < 2; i++) {
        int u = i * 512 + t, row = u >> 4, g = u & 15;   // g = cc*4+quad
        int off = (((p * 4 + (row >> 4)) * 4 + (g >> 2)) * 64 + (row & 15) * 4 + (g & 3)) * 8;
        *(bf16x8*)(xbT + (size_t)b * 524288 + off) =
            *(const bf16x8*)(sQ + row * 136 + g * 8);
    }
    // kmat rows PERMUTED within the 64-key tile: position pos holds key perm(pos),
    // perm(pos) = (k4&1)*32 + quad*8 + (k4>>1)*4 + r  (k4=pos>>4, quad=(pos>>2)&3, r=pos&3)
    // 16B chunk G stored at G ^ (pos&15) (matches flash's ^l16 read swizzle).
#pragma unroll
    for (int i = 0; i < 2; i++) {
        int u = i * 512 + t, pos = u >> 4, G = u & 15;
        int k4 = pos >> 4, sub = pos & 15;
        int src = (k4 & 1) * 32 + (sub >> 2) * 8 + (k4 >> 1) * 4 + (sub & 3);
        float iv = sInv[src];
        f32x4 a = *(const f32x4*)(sMidT + src * 132 + G * 8);
        f32x4 c = *(const f32x4*)(sMidT + src * 132 + G * 8 + 4);
        unsigned int w[4];
        w[0] = cvtpk(a[0] * iv, a[1] * iv);
        w[1] = cvtpk(a[2] * iv, a[3] * iv);
        w[2] = cvtpk(c[0] * iv, c[1] * iv);
        w[3] = cvtpk(c[2] * iv, c[3] * iv);
        int Gs = G ^ (pos & 15);
        *(uint4*)(kmat + ((size_t)b * 4096 + p * 64 + pos) * 128 + Gs * 8) =
            make_uint4(w[0], w[1], w[2], w[3]);
    }
    // kT rows (V, natural key order): within each 64-key tile, 8-key chunk h at h ^ (c&7)
    {
        int cl = t >> 2, qg = t & 3;
        unsigned int w[8];
#pragma unroll
        for (int j = 0; j < 8; j++) {
            int ql = qg * 16 + j * 2;
            w[j] = cvtpk(sMidT[ql * 132 + cl] * sInv[ql],
                         sMidT[(ql + 1) * 132 + cl] * sInv[ql + 1]);
        }
        unsigned short* dst = kT + ((size_t)b * 128 + cl) * 4096 + p * 64;
        int h0 = (qg * 2) ^ (cl & 7), h1 = (qg * 2 + 1) ^ (cl & 7);
        *(uint4*)(dst + h0 * 8) = make_uint4(w[0], w[1], w[2], w[3]);
        *(uint4*)(dst + h1 * 8) = make_uint4(w[4], w[5], w[6], w[7]);
    }
}

// ---------------- K2: split-K flash, 512 thr, 2-tile barrier pairs, XCD-grouped ----------
#define TILE_STRIDE 16384              // u16: one tile = sK 8192 + sV 8192
#define PAIR_STRIDE 32768              // u16: two tiles
#define SMEM_ELEMS  65536              // u16 = 131072 B -> 1 block/CU (fits 160K pool)

__global__ void __launch_bounds__(512, 2) flash_attn(
        const unsigned short* __restrict__ kmat,
        const unsigned short* __restrict__ kT,
        const unsigned short* __restrict__ xbT,
        unsigned short* __restrict__ opart,
        float* __restrict__ lsum,
        int nsplit, int qbshift) {
    // XCD-aware decode: idx%8 = XCD slot; the 16 qb-blocks of each (split,b) group share
    // one slot -> group's kmat/kT working set stays in that XCD's L2. Bijective for S>=2.
    const int idx = blockIdx.x;
    const int xs = idx & 7, j = idx >> 3;
    const int qb = j & 15;                         // 256-query tile, 0..15
    const int grp = xs * (nsplit >> 1) + (j >> 4); // 0..4*nsplit-1
    const int split = grp >> 2, b = grp & 3;
    const int nk = 4096 / nsplit, NIT = nk >> 6, kt_base = split * nk;
    const int NPAIR = NIT >> 1;
    const int t = threadIdx.x;
    const int wave = t >> 6, lane = t & 63;        // wave 0..7
    const int l16 = lane & 15, quad = lane >> 4;

    __shared__ __align__(16) unsigned short smem[SMEM_ELEMS];

    // Q frags from fragment-ordered xbT: qtile = qb*16 + wave*2 + h (32 q per wave)
    const unsigned short* xqb = xbT + (size_t)b * 524288 +
                                (size_t)(qb * 16 + wave * 2) * 2048 + (l16 * 4 + quad) * 8;
    bf16x8 aq[2][4];
#pragma unroll
    for (int h = 0; h < 2; h++)
#pragma unroll
        for (int cc = 0; cc < 4; cc++)
            aq[h][cc] = *(const bf16x8*)(xqb + h * 2048 + cc * 512);

    f32x4 o[2][8];
#pragma unroll
    for (int h = 0; h < 2; h++)
#pragma unroll
        for (int n = 0; n < 8; n++) o[h][n] = (f32x4){0.f, 0.f, 0.f, 0.f};
    float rs[2] = {0.f, 0.f};

    const unsigned short* kmb = kmat + (size_t)b * 4096 * 128;
    const unsigned short* ktb = kT + (size_t)b * 128 * 4096;

    // preload pair 0 into pair-buffer 0 (per tile: 8 waves x 2 issues K + 2 issues V)
#pragma unroll
    for (int half = 0; half < 2; half++) {
        const int kt0 = kt_base + half * 64;
        unsigned short* nb = smem + half * TILE_STRIDE;
        const unsigned short* gK = kmb + (size_t)kt0 * 128;
#pragma unroll
        for (int i = 0; i < 2; i++) {
            int e = i * 4096 + t * 8;
            gl_lds16(gK + e, nb + i * 4096 + wave * 512);
            gl_lds16(ktb + (size_t)(e >> 6) * 4096 + kt0 + (e & 63),
                     nb + 8192 + i * 4096 + wave * 512);
        }
    }

    for (int ip = 0; ip < NPAIR; ip++) {
        const int base = (ip & 1) * PAIR_STRIDE;

        // sole barrier per PAIR: drains this pair's DMA; all waves past it -> other
        // pair-buffer fully read (pair ip-1 compute preceded this barrier) -> reusable.
        __syncthreads();

        // issue next pair's DMA immediately: latency window = two tiles of compute
        if (ip + 1 < NPAIR) {
            unsigned short* pb = smem + ((ip + 1) & 1) * PAIR_STRIDE;
#pragma unroll
            for (int half = 0; half < 2; half++) {
                const int kt0 = kt_base + (2 * (ip + 1) + half) * 64;
                unsigned short* nb = pb + half * TILE_STRIDE;
                const unsigned short* gK = kmb + (size_t)kt0 * 128;
#pragma unroll
                for (int i = 0; i < 2; i++) {
                    int e = i * 4096 + t * 8;
                    gl_lds16(gK + e, nb + i * 4096 + wave * 512);
                    gl_lds16(ktb + (size_t)(e >> 6) * 4096 + kt0 + (e & 63),
                             nb + 8192 + i * 4096 + wave * 512);
                }
            }
        }

#pragma unroll
        for (int sub = 0; sub < 2; sub++) {
            unsigned short* sK = smem + base + sub * TILE_STRIDE;   // [64 pos][128], swz
            unsigned short* sV = sK + 8192;                         // [128 c][64 key], swz

            // S^T = K Q^T: lane holds S^T[pos = k4*16 + quad*4 + r][q = l16];
            // pos maps to key perm(pos) = (k4&1)*32 + quad*8 + (k4>>1)*4 + r.
            f32x4 s[2][4];
#pragma unroll
            for (int h = 0; h < 2; h++)
#pragma unroll
                for (int k4 = 0; k4 < 4; k4++) s[h][k4] = (f32x4){0.f, 0.f, 0.f, 0.f};
            __builtin_amdgcn_s_setprio(1);
#pragma unroll
            for (int cc = 0; cc < 4; cc++) {
#pragma unroll
                for (int k4 = 0; k4 < 4; k4++) {
                    bf16x8 ak = *(const bf16x8*)(sK + (k4 * 16 + l16) * 128 +
                                                 (((cc * 4 + quad) ^ l16) * 8));
                    s[0][k4] = __builtin_amdgcn_mfma_f32_16x16x32_bf16(ak, aq[0][cc], s[0][k4], 0, 0, 0);
                    s[1][k4] = __builtin_amdgcn_mfma_f32_16x16x32_bf16(ak, aq[1][cc], s[1][k4], 0, 0, 0);
                }
            }
            __builtin_amdgcn_s_setprio(0);

            // p = 2^s; row-sum; pack straight into PV B-operand fragments (no LDS):
            // pa[h][kc][j] = P[key = kc*32 + quad*8 + j][q=l16]:
            //   j=0..3 from s[h][kc][r], j=4..7 from s[h][kc+2][r].
            bf16x8 pa[2][2];
#pragma unroll
            for (int h = 0; h < 2; h++) {
                float pv[4][4];
#pragma unroll
                for (int k4 = 0; k4 < 4; k4++) {
#pragma unroll
                    for (int r = 0; r < 4; r++) {
                        float p = __builtin_amdgcn_exp2f(s[h][k4][r]);
                        pv[k4][r] = p;
                        rs[h] += p;
                    }
                }
#pragma unroll
                for (int kc = 0; kc < 2; kc++) {
                    u32x4 w;
                    w[0] = cvtpk(pv[kc][0], pv[kc][1]);
                    w[1] = cvtpk(pv[kc][2], pv[kc][3]);
                    w[2] = cvtpk(pv[kc + 2][0], pv[kc + 2][1]);
                    w[3] = cvtpk(pv[kc + 2][2], pv[kc + 2][3]);
                    pa[h][kc] = __builtin_bit_cast(bf16x8, w);
                }
            }

            // O[c][q] += V^T P : A = V^T rows from sV (swizzled), B = pa (registers).
            __builtin_amdgcn_s_setprio(1);
#pragma unroll
            for (int kc = 0; kc < 2; kc++)
#pragma unroll
                for (int n = 0; n < 8; n++) {
                    bf16x8 av = *(const bf16x8*)(sV + (n * 16 + l16) * 64 +
                                                 (((kc * 4 + quad) ^ (l16 & 7)) * 8));
                    o[0][n] = __builtin_amdgcn_mfma_f32_16x16x32_bf16(av, pa[0][kc], o[0][n], 0, 0, 0);
                    o[1][n] = __builtin_amdgcn_mfma_f32_16x16x32_bf16(av, pa[1][kc], o[1][n], 0, 0, 0);
                }
            __builtin_amdgcn_s_setprio(0);
        }
    }

    // row-sums reduce across quads; store lsum
#pragma unroll
    for (int h = 0; h < 2; h++) {
        rs[h] += __shfl_xor(rs[h], 16);
        rs[h] += __shfl_xor(rs[h], 32);
    }
    if (lane < 16) {
#pragma unroll
        for (int h = 0; h < 2; h++)
            lsum[(size_t)(split * 4 + b) * 4096 + qb * 256 + wave * 32 + h * 16 + lane] = rs[h];
    }

    // epilogue: o[h][n][r] = O[c = n*16+quad*4+r][q = wave*32+h*16+l16].
    // stage sO [256 q][136 c] u16 = 69632 B (aliases smem), then coalesced [q][c] store.
    __syncthreads();
    unsigned short* sO = smem;
    unsigned int* sO32 = (unsigned int*)smem;
#pragma unroll
    for (int h = 0; h < 2; h++) {
        int q = wave * 32 + h * 16 + l16;
#pragma unroll
        for (int n = 0; n < 8; n++) {
            int cb = n * 16 + quad * 4;
            sO32[(q * 136 + cb) >> 1] = cvtpk(o[h][n][0], o[h][n][1]);
            sO32[(q * 136 + cb + 2) >> 1] = cvtpk(o[h][n][2], o[h][n][3]);
        }
    }
    __syncthreads();
#pragma unroll
    for (int i = 0; i < 8; i++) {
        int u = i * 512 + t, q = u >> 4, ch = u & 15;
        *(uint4*)(opart + ((size_t)(split * 4 + b) * 4096 + qb * 256 + q) * 128 + ch * 8) =
            *(const uint4*)(sO + q * 136 + ch * 8);
    }
}

// ---------------- K3: combine splits + mask blend (opart [q][c]) -------------------------
// grid (64 qb64, 4 b, 2 cz) x 256: block = 64 q x 64 c. LDS transpose stage.
__global__ void combine(const unsigned short* __restrict__ opart,
                        const float* __restrict__ lsum,
                        const float* __restrict__ x,
                        const float* __restrict__ mask,
                        float* __restrict__ out, int S) {
    const int qb = blockIdx.x, b = blockIdx.y, cz = blockIdx.z, t = threadIdx.x;
    __shared__ float Linv[64];
    __shared__ float sAcc[64][73];       // [q local][c local], +pad for transpose reads
    if (t < 64) {
        float L = 0.f;
        for (int s2 = 0; s2 < S; s2++)
            L += lsum[(size_t)(s2 * 4 + b) * 4096 + qb * 64 + t];
        Linv[t] = 1.f / fmaxf(L, 1e-37f);
    }
    // phase 1: coalesced opart [q][c] reads, split-sum, stage to LDS
#pragma unroll
    for (int i = 0; i < 2; i++) {
        int u = i * 256 + t, qr = u >> 3, ch = u & 7;
        const unsigned short* ob = opart +
            ((size_t)b * 4096 + qb * 64 + qr) * 128 + cz * 64 + ch * 8;
        float acc[8] = {0.f, 0.f, 0.f, 0.f, 0.f, 0.f, 0.f, 0.f};
        if (S == 4) {
            u16x8 p0 = *(const u16x8*)(ob);
            u16x8 p1 = *(const u16x8*)(ob + (size_t)1 * 2097152);
            u16x8 p2 = *(const u16x8*)(ob + (size_t)2 * 2097152);
            u16x8 p3 = *(const u16x8*)(ob + (size_t)3 * 2097152);
#pragma unroll
            for (int j = 0; j < 8; j++)
                acc[j] = (bf2f(p0[j]) + bf2f(p1[j])) + (bf2f(p2[j]) + bf2f(p3[j]));
        } else {
            for (int s2 = 0; s2 < S; s2++) {
                u16x8 pv = *(const u16x8*)(ob + (size_t)s2 * 2097152);
#pragma unroll
                for (int j = 0; j < 8; j++) acc[j] += bf2f(pv[j]);
            }
        }
#pragma unroll
        for (int j = 0; j < 8; j++) sAcc[qr][ch * 8 + j] = acc[j];
    }
    __syncthreads();
    // phase 2: transposed LDS reads (padded stride), blend with x/mask (coalesced)
#pragma unroll
    for (int i = 0; i < 2; i++) {
        int u = i * 256 + t, cl = u >> 3, c = cz * 64 + cl, qc = u & 7;
        size_t qoff = (size_t)qb * 64 + qc * 8;
        const float* xr = x + ((size_t)b * 128 + c) * 4096 + qoff;
        const float* mr = mask + (size_t)b * 4096 + qoff;
        float* outr = out + ((size_t)b * 128 + c) * 4096 + qoff;
#pragma unroll
        for (int half = 0; half < 2; half++) {
            f32x4 xv = *(const f32x4*)(xr + half * 4);
            f32x4 mv = *(const f32x4*)(mr + half * 4);
            f32x4 res;
#pragma unroll
            for (int j = 0; j < 4; j++) {
                int ql = qc * 8 + half * 4 + j;
                res[j] = sAcc[ql][cl] * Linv[ql] *
                         (1.f - mv[j]) * (1.f / 9.f) + xv[j] * mv[j];
            }
            *(f32x4*)(outr + half * 4) = res;
        }
    }
}

extern "C" void kernel_launch(void* const* d_in, const int* in_sizes, int n_in,
                              void* d_out, int out_size, void* d_ws, size_t ws_size,
                              hipStream_t stream) {
    const float* x = (const float*)d_in[0];     // f32 (4,128,64,64)
    const float* mask = (const float*)d_in[1];  // f32 (4,1,64,64)
    float* out = (float*)d_out;                 // f32 (4,128,64,64)
    char* ws = (char*)d_ws;
    unsigned short* kmat = (unsigned short*)(ws);
    unsigned short* kT   = (unsigned short*)(ws + (size_t)4 * 1024 * 1024);
    unsigned short* xbT  = (unsigned short*)(ws + (size_t)8 * 1024 * 1024);
    float* lsum          = (float*)(ws + (size_t)12 * 1024 * 1024);
    unsigned short* opart = (unsigned short*)(ws + (size_t)13 * 1024 * 1024);

    // ws need: 13 MiB + S*4 MiB; S=4 -> flash grid 16*4*4 = 256 blocks = 1/CU
    int S, qbshift;
    if (ws_size >= (size_t)29 * 1024 * 1024)      { S = 4; qbshift = 4; }
    else if (ws_size >= (size_t)21 * 1024 * 1024) { S = 2; qbshift = 3; }
    else return;

    prep<<<dim3(64, 4), 512, 0, stream>>>(x, kmat, kT, xbT);
    flash_attn<<<dim3(16 * 4 * S), 512, 0, stream>>>(kmat, kT, xbT, opart, lsum, S, qbshift);
    combine<<<dim3(64, 4, 2), 256, 0, stream>>>(opart, lsum, x, mask, out, S);
}

// Round 15
// 109.751 us; speedup vs baseline: 1.0390x; 1.0087x over previous
//
#include <hip/hip_runtime.h>

// CAttention on MI355X (gfx950). Inputs f32, output f32.
// Q = box3(x)*log2(e), K = V = normalize(x+EPS), softmax over keys, per batch.
// Round 30: R14 (verified best, 110.7us) + combine TLP/vectorization. Combine was
// ~12us vs ~5us BW floor (latency-bound: 2 blocks/CU, 16 scalar LDS reads/thread).
// Change: c split 4-ways (grid 64x4x4, 32 c/block) -> sAcc 8.7KB -> 4 blocks/CU
// = 16 waves/CU; sAcc transposed to [c][q] so phase-2 reads are 2x f32x4 loads.
// flash + prep byte-identical to R14 (pair-barriers, XCD decode, P-in-regs permute,
// cvt_pk_bf16 packing, async-DMA prep).
// ws: kmat bf16 @0 | kT bf16 @4M | xbT bf16 @8M | lsum f32 @12M | opart bf16 @13M (S*4M).

typedef short bf16x8 __attribute__((ext_vector_type(8)));
typedef float f32x4 __attribute__((ext_vector_type(4)));
typedef unsigned short u16x8 __attribute__((ext_vector_type(8)));
typedef unsigned int u32x4 __attribute__((ext_vector_type(4)));

#define L2E 1.4426950408889634f

__device__ __forceinline__ unsigned short f2bf(float f) {
    unsigned int u;
    __builtin_memcpy(&u, &f, 4);
    u = u + 0x7FFFu + ((u >> 16) & 1u);   // RNE
    return (unsigned short)(u >> 16);
}
__device__ __forceinline__ float bf2f(unsigned short h) {
    unsigned int u = ((unsigned int)h) << 16;
    float f;
    __builtin_memcpy(&f, &u, 4);
    return f;
}
// packed f32x2 -> bf16x2 (low16 from a, high16 from b), single HW instruction (RNE)
__device__ __forceinline__ unsigned int cvtpk(float a, float b) {
    unsigned int r;
    asm("v_cvt_pk_bf16_f32 %0, %1, %2" : "=v"(r) : "v"(a), "v"(b));
    return r;
}
// async global->LDS, 16B/lane; lptr wave-uniform (HW dst = lptr + lane*16)
__device__ __forceinline__ void gl_lds16(const unsigned short* g, unsigned short* l) {
    __builtin_amdgcn_global_load_lds(
        (const __attribute__((address_space(1))) unsigned int*)g,
        (__attribute__((address_space(3))) unsigned int*)l, 16, 0, 0);
}
// async global->LDS, 4B/lane; g is per-lane, l wave-uniform (HW dst = l + lane*4)
__device__ __forceinline__ void gl_lds4(const float* g, float* l) {
    __builtin_amdgcn_global_load_lds(
        (const __attribute__((address_space(1))) unsigned int*)g,
        (__attribute__((address_space(3))) unsigned int*)l, 4, 0, 0);
}

// ---------------- K1: fused prep, async-DMA double-buffered chunks -----------------------
// grid (64 p, 4 b) x 512: block = one p-row (64 q), all 128 c in 8 chunks of 16.
__global__ void __launch_bounds__(512) prep(const float* __restrict__ x,
                     unsigned short* __restrict__ kmat,
                     unsigned short* __restrict__ kT,
                     unsigned short* __restrict__ xbT) {
    const int p = blockIdx.x, b = blockIdx.y;
    const int t = threadIdx.x, wave = t >> 6, lane = t & 63;

    __shared__ float sX[2][16][3][66];    // double-buffered chunk: 16 ch x 3 rows x 64+halo
    __shared__ float sMidT[64 * 132];     // [q][c], f32, stride 132
    __shared__ __align__(16) unsigned short sQ[64 * 136];
    __shared__ float sqp[512];
    __shared__ float sInv[64];

    // zero the q-halo columns once (DMA only ever writes elements [1..64])
    if (t < 192) {
        int bu = t / 96, u = t % 96, side = u & 1, v = u >> 1;   // v < 48
        int r = v % 3, cc = v / 3;
        sX[bu][cc][r][side * 65] = 0.f;
    }

    // issue chunk 0 DMA (wave-uniform (cc,r) per issue; 1 row = 64 lanes x 4B)
#pragma unroll
    for (int i = 0; i < 6; i++) {
        int pair = wave * 6 + i;
        int cc = pair / 3, r = pair - cc * 3, pp = p + r - 1;
        if ((unsigned)pp < 64u)
            gl_lds4(x + ((size_t)(b * 128 + cc) * 4096 + pp * 64) + lane,
                    &sX[0][cc][r][1]);
        else
            sX[0][cc][r][1 + lane] = 0.f;
    }

    float sqacc = 0.f;
    for (int k = 0; k < 8; k++) {
        __syncthreads();                              // chunk k DMA + writes drained
        if (k < 7) {                                  // issue chunk k+1 into other buffer
            int c0n = (k + 1) * 16, bn = (k + 1) & 1;
#pragma unroll
            for (int i = 0; i < 6; i++) {
                int pair = wave * 6 + i;
                int cc = pair / 3, r = pair - cc * 3, pp = p + r - 1;
                if ((unsigned)pp < 64u)
                    gl_lds4(x + ((size_t)(b * 128 + c0n + cc) * 4096 + pp * 64) + lane,
                            &sX[bn][cc][r][1]);
                else
                    sX[bn][cc][r][1 + lane] = 0.f;
            }
        }
        const int c0 = k * 16, kb = k & 1;
#pragma unroll
        for (int j = 0; j < 2; j++) {
            int cc = wave * 2 + j;
            float mid = sX[kb][cc][1][1 + lane] + 1e-7f;
            sMidT[lane * 132 + c0 + cc] = mid;
            sqacc += mid * mid;
            float sbox = 0.f;
#pragma unroll
            for (int r = 0; r < 3; r++)
                sbox += sX[kb][cc][r][lane] + sX[kb][cc][r][lane + 1] + sX[kb][cc][r][lane + 2];
            sQ[lane * 136 + c0 + cc] = f2bf(sbox * L2E);
        }
    }
    sqp[t] = sqacc;
    __syncthreads();
    if (t < 64) {
        float s = 0.f;
#pragma unroll
        for (int w = 0; w < 8; w++) s += sqp[w * 64 + t];
        sInv[t] = rsqrtf(s);
    }
    __syncthreads();

    // xbT in MFMA-fragment order: elem(b, qtile, cc, l16, quad, j) at
    // ((qtile*4+cc)*64 + l16*4 + quad)*8 + j  => Q[q=qtile*16+l16][c=cc*32+quad*8+j]
#pragma unroll
    for (int i = 0; i < 2; i++) {
        int u = i * 512 + t, row = u >> 4, g = u & 15;   // g = cc*4+quad
        int off = (((p * 4 + (row >> 4)) * 4 + (g >> 2)) * 64 + (row & 15) * 4 + (g & 3)) * 8;
        *(bf16x8*)(xbT + (size_t)b * 524288 + off) =
            *(const bf16x8*)(sQ + row * 136 + g * 8);
    }
    // kmat rows PERMUTED within the 64-key tile: position pos holds key perm(pos),
    // perm(pos) = (k4&1)*32 + quad*8 + (k4>>1)*4 + r  (k4=pos>>4, quad=(pos>>2)&3, r=pos&3)
    // 16B chunk G stored at G ^ (pos&15) (matches flash's ^l16 read swizzle).
#pragma unroll
    for (int i = 0; i < 2; i++) {
        int u = i * 512 + t, pos = u >> 4, G = u & 15;
        int k4 = pos >> 4, sub = pos & 15;
        int src = (k4 & 1) * 32 + (sub >> 2) * 8 + (k4 >> 1) * 4 + (sub & 3);
        float iv = sInv[src];
        f32x4 a = *(const f32x4*)(sMidT + src * 132 + G * 8);
        f32x4 c = *(const f32x4*)(sMidT + src * 132 + G * 8 + 4);
        unsigned int w[4];
        w[0] = cvtpk(a[0] * iv, a[1] * iv);
        w[1] = cvtpk(a[2] * iv, a[3] * iv);
        w[2] = cvtpk(c[0] * iv, c[1] * iv);
        w[3] = cvtpk(c[2] * iv, c[3] * iv);
        int Gs = G ^ (pos & 15);
        *(uint4*)(kmat + ((size_t)b * 4096 + p * 64 + pos) * 128 + Gs * 8) =
            make_uint4(w[0], w[1], w[2], w[3]);
    }
    // kT rows (V, natural key order): within each 64-key tile, 8-key chunk h at h ^ (c&7)
    {
        int cl = t >> 2, qg = t & 3;
        unsigned int w[8];
#pragma unroll
        for (int j = 0; j < 8; j++) {
            int ql = qg * 16 + j * 2;
            w[j] = cvtpk(sMidT[ql * 132 + cl] * sInv[ql],
                         sMidT[(ql + 1) * 132 + cl] * sInv[ql + 1]);
        }
        unsigned short* dst = kT + ((size_t)b * 128 + cl) * 4096 + p * 64;
        int h0 = (qg * 2) ^ (cl & 7), h1 = (qg * 2 + 1) ^ (cl & 7);
        *(uint4*)(dst + h0 * 8) = make_uint4(w[0], w[1], w[2], w[3]);
        *(uint4*)(dst + h1 * 8) = make_uint4(w[4], w[5], w[6], w[7]);
    }
}

// ---------------- K2: split-K flash, 512 thr, 2-tile barrier pairs, XCD-grouped ----------
#define TILE_STRIDE 16384              // u16: one tile = sK 8192 + sV 8192
#define PAIR_STRIDE 32768              // u16: two tiles
#define SMEM_ELEMS  65536              // u16 = 131072 B -> 1 block/CU (fits 160K pool)

__global__ void __launch_bounds__(512, 2) flash_attn(
        const unsigned short* __restrict__ kmat,
        const unsigned short* __restrict__ kT,
        const unsigned short* __restrict__ xbT,
        unsigned short* __restrict__ opart,
        float* __restrict__ lsum,
        int nsplit, int qbshift) {
    // XCD-aware decode: idx%8 = XCD slot; the 16 qb-blocks of each (split,b) group share
    // one slot -> group's kmat/kT working set stays in that XCD's L2. Bijective for S>=2.
    const int idx = blockIdx.x;
    const int xs = idx & 7, j = idx >> 3;
    const int qb = j & 15;                         // 256-query tile, 0..15
    const int grp = xs * (nsplit >> 1) + (j >> 4); // 0..4*nsplit-1
    const int split = grp >> 2, b = grp & 3;
    const int nk = 4096 / nsplit, NIT = nk >> 6, kt_base = split * nk;
    const int NPAIR = NIT >> 1;
    const int t = threadIdx.x;
    const int wave = t >> 6, lane = t & 63;        // wave 0..7
    const int l16 = lane & 15, quad = lane >> 4;

    __shared__ __align__(16) unsigned short smem[SMEM_ELEMS];

    // Q frags from fragment-ordered xbT: qtile = qb*16 + wave*2 + h (32 q per wave)
    const unsigned short* xqb = xbT + (size_t)b * 524288 +
                                (size_t)(qb * 16 + wave * 2) * 2048 + (l16 * 4 + quad) * 8;
    bf16x8 aq[2][4];
#pragma unroll
    for (int h = 0; h < 2; h++)
#pragma unroll
        for (int cc = 0; cc < 4; cc++)
            aq[h][cc] = *(const bf16x8*)(xqb + h * 2048 + cc * 512);

    f32x4 o[2][8];
#pragma unroll
    for (int h = 0; h < 2; h++)
#pragma unroll
        for (int n = 0; n < 8; n++) o[h][n] = (f32x4){0.f, 0.f, 0.f, 0.f};
    float rs[2] = {0.f, 0.f};

    const unsigned short* kmb = kmat + (size_t)b * 4096 * 128;
    const unsigned short* ktb = kT + (size_t)b * 128 * 4096;

    // preload pair 0 into pair-buffer 0 (per tile: 8 waves x 2 issues K + 2 issues V)
#pragma unroll
    for (int half = 0; half < 2; half++) {
        const int kt0 = kt_base + half * 64;
        unsigned short* nb = smem + half * TILE_STRIDE;
        const unsigned short* gK = kmb + (size_t)kt0 * 128;
#pragma unroll
        for (int i = 0; i < 2; i++) {
            int e = i * 4096 + t * 8;
            gl_lds16(gK + e, nb + i * 4096 + wave * 512);
            gl_lds16(ktb + (size_t)(e >> 6) * 4096 + kt0 + (e & 63),
                     nb + 8192 + i * 4096 + wave * 512);
        }
    }

    for (int ip = 0; ip < NPAIR; ip++) {
        const int base = (ip & 1) * PAIR_STRIDE;

        // sole barrier per PAIR: drains this pair's DMA; all waves past it -> other
        // pair-buffer fully read (pair ip-1 compute preceded this barrier) -> reusable.
        __syncthreads();

        // issue next pair's DMA immediately: latency window = two tiles of compute
        if (ip + 1 < NPAIR) {
            unsigned short* pb = smem + ((ip + 1) & 1) * PAIR_STRIDE;
#pragma unroll
            for (int half = 0; half < 2; half++) {
                const int kt0 = kt_base + (2 * (ip + 1) + half) * 64;
                unsigned short* nb = pb + half * TILE_STRIDE;
                const unsigned short* gK = kmb + (size_t)kt0 * 128;
#pragma unroll
                for (int i = 0; i < 2; i++) {
                    int e = i * 4096 + t * 8;
                    gl_lds16(gK + e, nb + i * 4096 + wave * 512);
                    gl_lds16(ktb + (size_t)(e >> 6) * 4096 + kt0 + (e & 63),
                             nb + 8192 + i * 4096 + wave * 512);
                }
            }
        }

#pragma unroll
        for (int sub = 0; sub < 2; sub++) {
            unsigned short* sK = smem + base + sub * TILE_STRIDE;   // [64 pos][128], swz
            unsigned short* sV = sK + 8192;                         // [128 c][64 key], swz

            // S^T = K Q^T: lane holds S^T[pos = k4*16 + quad*4 + r][q = l16];
            // pos maps to key perm(pos) = (k4&1)*32 + quad*8 + (k4>>1)*4 + r.
            f32x4 s[2][4];
#pragma unroll
            for (int h = 0; h < 2; h++)
#pragma unroll
                for (int k4 = 0; k4 < 4; k4++) s[h][k4] = (f32x4){0.f, 0.f, 0.f, 0.f};
            __builtin_amdgcn_s_setprio(1);
#pragma unroll
            for (int cc = 0; cc < 4; cc++) {
#pragma unroll
                for (int k4 = 0; k4 < 4; k4++) {
                    bf16x8 ak = *(const bf16x8*)(sK + (k4 * 16 + l16) * 128 +
                                                 (((cc * 4 + quad) ^ l16) * 8));
                    s[0][k4] = __builtin_amdgcn_mfma_f32_16x16x32_bf16(ak, aq[0][cc], s[0][k4], 0, 0, 0);
                    s[1][k4] = __builtin_amdgcn_mfma_f32_16x16x32_bf16(ak, aq[1][cc], s[1][k4], 0, 0, 0);
                }
            }
            __builtin_amdgcn_s_setprio(0);

            // p = 2^s; row-sum; pack straight into PV B-operand fragments (no LDS):
            // pa[h][kc][j] = P[key = kc*32 + quad*8 + j][q=l16]:
            //   j=0..3 from s[h][kc][r], j=4..7 from s[h][kc+2][r].
            bf16x8 pa[2][2];
#pragma unroll
            for (int h = 0; h < 2; h++) {
                float pv[4][4];
#pragma unroll
                for (int k4 = 0; k4 < 4; k4++) {
#pragma unroll
                    for (int r = 0; r < 4; r++) {
                        float p = __builtin_amdgcn_exp2f(s[h][k4][r]);
                        pv[k4][r] = p;
                        rs[h] += p;
                    }
                }
#pragma unroll
                for (int kc = 0; kc < 2; kc++) {
                    u32x4 w;
                    w[0] = cvtpk(pv[kc][0], pv[kc][1]);
                    w[1] = cvtpk(pv[kc][2], pv[kc][3]);
                    w[2] = cvtpk(pv[kc + 2][0], pv[kc + 2][1]);
                    w[3] = cvtpk(pv[kc + 2][2], pv[kc + 2][3]);
                    pa[h][kc] = __builtin_bit_cast(bf16x8, w);
                }
            }

            // O[c][q] += V^T P : A = V^T rows from sV (swizzled), B = pa (registers).
            __builtin_amdgcn_s_setprio(1);
#pragma unroll
            for (int kc = 0; kc < 2; kc++)
#pragma unroll
                for (int n = 0; n < 8; n++) {
                    bf16x8 av = *(const bf16x8*)(sV + (n * 16 + l16) * 64 +
                                                 (((kc * 4 + quad) ^ (l16 & 7)) * 8));
                    o[0][n] = __builtin_amdgcn_mfma_f32_16x16x32_bf16(av, pa[0][kc], o[0][n], 0, 0, 0);
                    o[1][n] = __builtin_amdgcn_mfma_f32_16x16x32_bf16(av, pa[1][kc], o[1][n], 0, 0, 0);
                }
            __builtin_amdgcn_s_setprio(0);
        }
    }

    // row-sums reduce across quads; store lsum
#pragma unroll
    for (int h = 0; h < 2; h++) {
        rs[h] += __shfl_xor(rs[h], 16);
        rs[h] += __shfl_xor(rs[h], 32);
    }
    if (lane < 16) {
#pragma unroll
        for (int h = 0; h < 2; h++)
            lsum[(size_t)(split * 4 + b) * 4096 + qb * 256 + wave * 32 + h * 16 + lane] = rs[h];
    }

    // epilogue: o[h][n][r] = O[c = n*16+quad*4+r][q = wave*32+h*16+l16].
    // stage sO [256 q][136 c] u16 = 69632 B (aliases smem), then coalesced [q][c] store.
    __syncthreads();
    unsigned short* sO = smem;
    unsigned int* sO32 = (unsigned int*)smem;
#pragma unroll
    for (int h = 0; h < 2; h++) {
        int q = wave * 32 + h * 16 + l16;
#pragma unroll
        for (int n = 0; n < 8; n++) {
            int cb = n * 16 + quad * 4;
            sO32[(q * 136 + cb) >> 1] = cvtpk(o[h][n][0], o[h][n][1]);
            sO32[(q * 136 + cb + 2) >> 1] = cvtpk(o[h][n][2], o[h][n][3]);
        }
    }
    __syncthreads();
#pragma unroll
    for (int i = 0; i < 8; i++) {
        int u = i * 512 + t, q = u >> 4, ch = u & 15;
        *(uint4*)(opart + ((size_t)(split * 4 + b) * 4096 + qb * 256 + q) * 128 + ch * 8) =
            *(const uint4*)(sO + q * 136 + ch * 8);
    }
}

// ---------------- K3: combine splits + mask blend (opart [q][c]) -------------------------
// grid (64 qb64, 4 b, 4 cz) x 256: block = 64 q x 32 c. sAcc transposed [c][q] so the
// blend phase reads f32x4; small LDS (~8.7KB) -> 4 blocks/CU = 16 waves (2x TLP vs R14).
__global__ void combine(const unsigned short* __restrict__ opart,
                        const float* __restrict__ lsum,
                        const float* __restrict__ x,
                        const float* __restrict__ mask,
                        float* __restrict__ out, int S) {
    const int qb = blockIdx.x, b = blockIdx.y, cz = blockIdx.z, t = threadIdx.x;
    __shared__ float Linv[64];
    __shared__ float sAcc[32][68];       // [c local][q local], +4 pad
    if (t < 64) {
        float L = 0.f;
        for (int s2 = 0; s2 < S; s2++)
            L += lsum[(size_t)(s2 * 4 + b) * 4096 + qb * 64 + t];
        Linv[t] = 1.f / fmaxf(L, 1e-37f);
    }
    // phase 1: coalesced opart [q][c] reads (32 c chunk), split-sum, scatter to sAcc[c][q]
    {
        int qr = t >> 2, ch = t & 3;
        const unsigned short* ob = opart +
            ((size_t)b * 4096 + qb * 64 + qr) * 128 + cz * 32 + ch * 8;
        float acc[8] = {0.f, 0.f, 0.f, 0.f, 0.f, 0.f, 0.f, 0.f};
        if (S == 4) {
            u16x8 p0 = *(const u16x8*)(ob);
            u16x8 p1 = *(const u16x8*)(ob + (size_t)1 * 2097152);
            u16x8 p2 = *(const u16x8*)(ob + (size_t)2 * 2097152);
            u16x8 p3 = *(const u16x8*)(ob + (size_t)3 * 2097152);
#pragma unroll
            for (int j = 0; j < 8; j++)
                acc[j] = (bf2f(p0[j]) + bf2f(p1[j])) + (bf2f(p2[j]) + bf2f(p3[j]));
        } else {
            for (int s2 = 0; s2 < S; s2++) {
                u16x8 pv = *(const u16x8*)(ob + (size_t)s2 * 2097152);
#pragma unroll
                for (int j = 0; j < 8; j++) acc[j] += bf2f(pv[j]);
            }
        }
#pragma unroll
        for (int j = 0; j < 8; j++) sAcc[ch * 8 + j][qr] = acc[j];
    }
    __syncthreads();
    // phase 2: vectorized sAcc[c][q] reads (f32x4), blend with x/mask (coalesced)
    {
        int cl = t >> 3, c = cz * 32 + cl, qc = t & 7;
        size_t qoff = (size_t)qb * 64 + qc * 8;
        const float* xr = x + ((size_t)b * 128 + c) * 4096 + qoff;
        const float* mr = mask + (size_t)b * 4096 + qoff;
        float* outr = out + ((size_t)b * 128 + c) * 4096 + qoff;
#pragma unroll
        for (int half = 0; half < 2; half++) {
            f32x4 av = *(const f32x4*)(&sAcc[cl][qc * 8 + half * 4]);
            f32x4 lv = *(const f32x4*)(&Linv[qc * 8 + half * 4]);
            f32x4 xv = *(const f32x4*)(xr + half * 4);
            f32x4 mv = *(const f32x4*)(mr + half * 4);
            f32x4 res;
#pragma unroll
            for (int j = 0; j < 4; j++)
                res[j] = av[j] * lv[j] * (1.f - mv[j]) * (1.f / 9.f) + xv[j] * mv[j];
            *(f32x4*)(outr + half * 4) = res;
        }
    }
}

extern "C" void kernel_launch(void* const* d_in, const int* in_sizes, int n_in,
                              void* d_out, int out_size, void* d_ws, size_t ws_size,
                              hipStream_t stream) {
    const float* x = (const float*)d_in[0];     // f32 (4,128,64,64)
    const float* mask = (const float*)d_in[1];  // f32 (4,1,64,64)
    float* out = (float*)d_out;                 // f32 (4,128,64,64)
    char* ws = (char*)d_ws;
    unsigned short* kmat = (unsigned short*)(ws);
    unsigned short* kT   = (unsigned short*)(ws + (size_t)4 * 1024 * 1024);
    unsigned short* xbT  = (unsigned short*)(ws + (size_t)8 * 1024 * 1024);
    float* lsum          = (float*)(ws + (size_t)12 * 1024 * 1024);
    unsigned short* opart = (unsigned short*)(ws + (size_t)13 * 1024 * 1024);

    // ws need: 13 MiB + S*4 MiB; S=4 -> flash grid 16*4*4 = 256 blocks = 1/CU
    int S, qbshift;
    if (ws_size >= (size_t)29 * 1024 * 1024)      { S = 4; qbshift = 4; }
    else if (ws_size >= (size_t)21 * 1024 * 1024) { S = 2; qbshift = 3; }
    else return;

    prep<<<dim3(64, 4), 512, 0, stream>>>(x, kmat, kT, xbT);
    flash_attn<<<dim3(16 * 4 * S), 512, 0, stream>>>(kmat, kT, xbT, opart, lsum, S, qbshift);
    combine<<<dim3(64, 4, 4), 256, 0, stream>>>(opart, lsum, x, mask, out, S);
}